// Round 11
// baseline (305.185 us; speedup 1.0000x reference)
//
#include <hip/hip_runtime.h>
#include <hip/hip_fp16.h>

#define NN 131072        // nodes
#define EE 2097152       // edges
#define SS 32            // channels
#define HH 16            // hidden
#define BB 4096          // graphs
#define EPS 1e-5f

#define BKT 512          // buckets (dst >> 8)
#define BNODES 256       // nodes per bucket
#define CAP 4864         // bucket capacity in words (avg 4096, +12 sigma)
#define SCAP 8192        // bucket capacity in ssrc (padded-to-8 per node)
#define TILE 8192        // edges per bsort block

typedef _Float16 f16x8 __attribute__((ext_vector_type(8)));
typedef float f32x4 __attribute__((ext_vector_type(4)));

// ---------------- bucket partition, LDS-staged, 1024 threads ----------------
__global__ __launch_bounds__(1024) void k_bsort(const int* __restrict__ ei, int* __restrict__ gcount,
                                                int* __restrict__ words) {
    __shared__ int cnt[BKT];
    __shared__ int tstart[BKT];
    __shared__ int gshift[BKT];
    __shared__ int sc[BKT];
    __shared__ int sword[TILE];
    __shared__ int sdst[TILE];
    int t = threadIdx.x;
    if (t < BKT) cnt[t] = 0;
    __syncthreads();
    int e0 = blockIdx.x * TILE;
    int dreg[TILE / 1024];
#pragma unroll
    for (int it = 0; it < TILE / 1024; ++it) {
        dreg[it] = ei[EE + e0 + it * 1024 + t];
        atomicAdd(&cnt[dreg[it] >> 8], 1);
    }
    __syncthreads();
    int val = (t < BKT) ? cnt[t] : 0;
    if (t < BKT) sc[t] = val;
    __syncthreads();
    for (int d = 1; d < BKT; d <<= 1) {
        int v2 = (t >= d && t < BKT) ? sc[t - d] : 0;
        __syncthreads();
        if (t < BKT) sc[t] += v2;
        __syncthreads();
    }
    if (t < BKT) {
        int excl = sc[t] - val;
        tstart[t] = excl;
        gshift[t] = t * CAP + atomicAdd(&gcount[t], val) - excl;   // includes segment base
        cnt[t] = 0;                     // reuse as intra-tile cursor
    }
    __syncthreads();
#pragma unroll
    for (int it = 0; it < TILE / 1024; ++it) {
        int e = e0 + it * 1024 + t;
        int src = ei[e];
        int dst = dreg[it];
        int b = dst >> 8;
        int r = atomicAdd(&cnt[b], 1);
        int p = tstart[b] + r;
        sword[p] = src | ((dst & 255) << 17);
        sdst[p] = gshift[b] + p;        // == b*CAP + bucket_base + rank
    }
    __syncthreads();
#pragma unroll
    for (int it = 0; it < TILE / 1024; ++it) {
        int i = it * 1024 + t;
        words[sdst[i]] = sword[i];      // position-ordered: full-line bursts
    }
}

// ---------------- within-bucket sort to CSR with 8-padded node segments ----------------
// R11: words stashed in LDS during pass 1 (19.5 KB, no VGPR-array spill risk);
// pass 2 reads LDS instead of re-reading 10 MB of words through L2.
__global__ __launch_bounds__(512) void k_csr(const int* __restrict__ words, const int* __restrict__ gcount,
                                             int* __restrict__ ssrc, int* __restrict__ offs,
                                             int* __restrict__ offe) {
    __shared__ int swords[CAP];
    __shared__ int hist[BNODES];
    __shared__ int sc[BNODES];
    __shared__ int base[BNODES];
    int t = threadIdx.x;
    int b = blockIdx.x;
    if (t < BNODES) hist[t] = 0;
    __syncthreads();
    int cnt = gcount[b];
    const int* wp = words + (size_t)b * CAP;
    for (int p = t; p < cnt; p += 512) {
        int w = wp[p];
        swords[p] = w;
        atomicAdd(&hist[w >> 17], 1);
    }
    __syncthreads();
    int val = 0, pval = 0;
    if (t < BNODES) {
        val = hist[t];
        pval = (val + 7) & ~7;          // padded length (pad-8)
        sc[t] = pval;
    }
    __syncthreads();
    for (int d = 1; d < BNODES; d <<= 1) {
        int v2 = (t >= d && t < BNODES) ? sc[t - d] : 0;
        __syncthreads();
        if (t < BNODES) sc[t] += v2;
        __syncthreads();
    }
    int gbase = b * SCAP;
    if (t < BNODES) {
        base[t] = sc[t] - pval;         // exclusive scan of padded lengths
        offs[b * BNODES + t] = gbase + base[t];
        offe[b * BNODES + t] = gbase + base[t] + val;
        hist[t] = 0;                    // reuse as per-node cursor
    }
    __syncthreads();
    for (int p = t; p < cnt; p += 512) {
        int w = swords[p];              // LDS re-read (was global)
        int dl = w >> 17;
        int r = atomicAdd(&hist[dl], 1);
        ssrc[gbase + base[dl] + r] = w & 0x1FFFF;
    }
    if (t < BNODES) {                   // pad fill: disjoint range [val, pval)
        int s = gbase + base[t];
        for (int i = val; i < pval; ++i) ssrc[s + i] = NN;
    }
}

// ---------------- fused prep: weight transposes + head fold + zero-init + layer-1 pre ----------------
__global__ __launch_bounds__(256) void k_prep(const float* __restrict__ mW1, const float* __restrict__ mW2,
                                              const float* __restrict__ mW3, const float* __restrict__ vW,
                                              const float* __restrict__ vb, const float* __restrict__ aW,
                                              const float* __restrict__ ab,
                                              _Float16* __restrict__ W1T, _Float16* __restrict__ W2T,
                                              _Float16* __restrict__ W3T, _Float16* __restrict__ BqT,
                                              float* __restrict__ biasq, int* __restrict__ gcount,
                                              float* __restrict__ bns,
                                              const float* __restrict__ x, const float* __restrict__ c1W1,
                                              const float* __restrict__ c1b1,
                                              float* __restrict__ u, __half* __restrict__ v) {
    int i = blockIdx.x * 256 + threadIdx.x;     // NN*16 = 2097152 threads
    {   // layer-1 pre-transform for every (node, hidden-ch)
        int n = i >> 4, c = i & 15;
        float x0 = x[n * 2], x1 = x[n * 2 + 1];
        float w0 = c1W1[c], w1 = c1W1[16 + c], w2 = c1W1[32 + c], w3 = c1W1[48 + c];
        u[i] = c1b1[c] + x0 * (w0 - w2) + x1 * (w1 - w3);
        v[i] = __float2half(x0 * w2 + x1 * w3);
    }
    if (i < 262144) {
        int k = i >> 8, n = i & 255;
        W1T[(size_t)n * 1024 + k] = (_Float16)mW1[i];
    }
    if (i < 65536) {
        int k = i >> 8, n = i & 255;
        W2T[n * 256 + k] = (_Float16)mW2[i];
        W3T[n * 256 + k] = (_Float16)mW3[i];
    }
    if (i < 16384) {
        int f = i >> 6, j = i & 63;
        int n = j >> 1, a = j & 1;
        float wa = aW[n * 512 + f * 2 + a];
        float wo = aW[n * 512 + f * 2 + (1 - a)];
        BqT[j * 256 + f] = (_Float16)(vW[f] + 0.5f * (wa - wo));
    }
    if (i < 64) biasq[i] = vb[0] + 0.5f * (ab[i] - ab[i ^ 1]);
    if (i < 512) gcount[i] = 0;
    if (i < 1536) bns[i] = 0.f;                 // 3 layers x 8 shadows x 64
    if (i < 16) v[NN * 16 + i] = __float2half(-60000.0f);
}

// ---------------- fused BN+ReLU + pre-transform for layers 2/3 ----------------
// R11: 64 nodes/block (grid 8192 -> 2048): weight staging + stats + launch
// overhead amortized 4x. sh grows to 64x33 (8.4 KB).
__global__ __launch_bounds__(256) void k_bnpre(const float* __restrict__ y, const float* __restrict__ bns,
                                               const float* __restrict__ g, const float* __restrict__ bb,
                                               const float* __restrict__ W1, const float* __restrict__ b1,
                                               float* __restrict__ u, __half* __restrict__ v) {
    __shared__ float sh[64][33];
    __shared__ float wd[32][16];
    __shared__ float wv[32][16];
    __shared__ float scL[32], soL[32];
    int t = threadIdx.x;
    if (t < 32) {
        float sm = 0.f, sq = 0.f;
#pragma unroll
        for (int s = 0; s < 8; ++s) { sm += bns[s * 64 + t]; sq += bns[s * 64 + 32 + t]; }
        const float inv_n = 1.0f / (float)NN;
        float mean = sm * inv_n;
        float var = sq * inv_n - mean * mean;
        float s2 = g[t] * rsqrtf(var + EPS);
        scL[t] = s2;
        soL[t] = bb[t] - mean * s2;
    }
    for (int i = t; i < 512; i += 256) {
        int f = i >> 4, c = i & 15;
        float wt = W1[i];
        float wb = W1[512 + i];
        wd[f][c] = wt - wb;
        wv[f][c] = wb;
    }
    __syncthreads();
    int nb = blockIdx.x * 64;
    for (int i = t; i < 2048; i += 256) {
        int col = i & 31;
        sh[i >> 5][col] = fmaxf(y[nb * 32 + i] * scL[col] + soL[col], 0.f);
    }
    __syncthreads();
    int c = t & 15;
#pragma unroll
    for (int r4 = 0; r4 < 4; ++r4) {
        int nl = r4 * 16 + (t >> 4);
        float uu = b1[c], vv = 0.f;
#pragma unroll
        for (int f = 0; f < 32; ++f) {
            float hv = sh[nl][f];
            uu += hv * wd[f][c];
            vv += hv * wv[f][c];
        }
        int n = nb + nl;
        u[n * 16 + c] = uu;
        v[n * 16 + c] = __float2half(vv);
    }
    if (blockIdx.x == 0 && t < 16) v[NN * 16 + t] = __float2half(-60000.0f);
}

// ---------------- CSR gather + fused BN-stat accumulation ----------------
__global__ __launch_bounds__(256) void k_gather(const float* __restrict__ u, const __half* __restrict__ v,
                                                const int* __restrict__ ssrc, const int* __restrict__ offs,
                                                const int* __restrict__ offe,
                                                const float* __restrict__ W2, const float* __restrict__ b2,
                                                float* __restrict__ y, float* __restrict__ bns) {
    __shared__ float sw2[512];          // [k][32]
    __shared__ float sagg[64 * 17];
    __shared__ float cntL[64];
    __shared__ float ssum[32];
    __shared__ float ssq[32];
    int t = threadIdx.x;
    if (t < 32) { ssum[t] = 0.f; ssq[t] = 0.f; }
    float w2a = W2[t], w2b = W2[t + 256];         // stage in regs; LDS write after gather
    float b2r0 = b2[(t & 7) * 4], b2r1 = b2[(t & 7) * 4 + 1];
    float b2r2 = b2[(t & 7) * 4 + 2], b2r3 = b2[(t & 7) * 4 + 3];
    int nl = t >> 2, c4 = t & 3;        // 64 nodes/block, 4 threads/node
    int n = blockIdx.x * 64 + nl;
    int s0 = offs[n], e0 = offe[n];
    int pe = s0 + ((e0 - s0 + 7) & ~7);           // padded end (pad slots -> node NN -> relu 0)
    float4 uc = *(const float4*)(u + (size_t)n * 16 + 4 * c4);
    float a0 = 0.f, a1 = 0.f, a2 = 0.f, a3 = 0.f;
    for (int p = s0; p < pe; p += 8) {
        int idx[8];
#pragma unroll
        for (int i = 0; i < 8; ++i) idx[i] = ssrc[p + i];
        uint2 hv[8];
#pragma unroll
        for (int i = 0; i < 8; ++i)
            hv[i] = *(const uint2*)(v + (size_t)idx[i] * 16 + 4 * c4);
#pragma unroll
        for (int i = 0; i < 8; ++i) {
            float2 f01 = __half22float2(*(const __half2*)&hv[i].x);
            float2 f23 = __half22float2(*(const __half2*)&hv[i].y);
            a0 += fmaxf(uc.x + f01.x, 0.f);
            a1 += fmaxf(uc.y + f01.y, 0.f);
            a2 += fmaxf(uc.z + f23.x, 0.f);
            a3 += fmaxf(uc.w + f23.y, 0.f);
        }
    }
    sagg[nl * 17 + 4 * c4]     = a0;
    sagg[nl * 17 + 4 * c4 + 1] = a1;
    sagg[nl * 17 + 4 * c4 + 2] = a2;
    sagg[nl * 17 + 4 * c4 + 3] = a3;
    if (c4 == 0) cntL[nl] = (float)(e0 - s0);
    sw2[t] = w2a;
    sw2[t + 256] = w2b;
    __syncthreads();
#pragma unroll
    for (int h = 0; h < 2; ++h) {       // two 32-node passes of the proven epilogue
        int node = h * 32 + (t >> 3), oc = (t & 7) * 4;
        float cw = cntL[node];
        float o0 = b2r0 * cw, o1 = b2r1 * cw, o2 = b2r2 * cw, o3 = b2r3 * cw;
#pragma unroll
        for (int k = 0; k < 16; ++k) {
            float a = sagg[node * 17 + k];
            o0 += a * sw2[k * 32 + oc];
            o1 += a * sw2[k * 32 + oc + 1];
            o2 += a * sw2[k * 32 + oc + 2];
            o3 += a * sw2[k * 32 + oc + 3];
        }
        *(float4*)(y + (size_t)(blockIdx.x * 64 + node) * 32 + oc) = make_float4(o0, o1, o2, o3);
        // fused BN stats: reduce o and o^2 over the 8 nodes of this wave
        float q0 = o0 * o0, q1 = o1 * o1, q2 = o2 * o2, q3 = o3 * o3;
#pragma unroll
        for (int m = 8; m < 64; m <<= 1) {
            o0 += __shfl_xor(o0, m); o1 += __shfl_xor(o1, m);
            o2 += __shfl_xor(o2, m); o3 += __shfl_xor(o3, m);
            q0 += __shfl_xor(q0, m); q1 += __shfl_xor(q1, m);
            q2 += __shfl_xor(q2, m); q3 += __shfl_xor(q3, m);
        }
        if ((t & 63) < 8) {             // one lane per channel-quad per wave
            atomicAdd(&ssum[oc], o0);     atomicAdd(&ssum[oc + 1], o1);
            atomicAdd(&ssum[oc + 2], o2); atomicAdd(&ssum[oc + 3], o3);
            atomicAdd(&ssq[oc], q0);      atomicAdd(&ssq[oc + 1], q1);
            atomicAdd(&ssq[oc + 2], q2);  atomicAdd(&ssq[oc + 3], q3);
        }
    }
    __syncthreads();
    if (t < 64) {
        float val = (t < 32) ? ssum[t] : ssq[t - 32];
        atomicAdd(&bns[(blockIdx.x & 7) * 64 + t], val);
    }
}

// ---------------- fused MLP + dueling head (+ layer-3 BN+ReLU inline) ----------------
__global__ __launch_bounds__(256) void k_mlp(const float* __restrict__ Y, const float* __restrict__ bns3,
                                             const float* __restrict__ g3, const float* __restrict__ b3,
                                             const _Float16* __restrict__ W1T,
                                             const _Float16* __restrict__ W2T, const _Float16* __restrict__ W3T,
                                             const _Float16* __restrict__ BqT,
                                             const float* __restrict__ mb1, const float* __restrict__ mb2,
                                             const float* __restrict__ mb3, const float* __restrict__ biasq,
                                             float* __restrict__ out) {
    __shared__ _Float16 sX[16 * 264];
    __shared__ _Float16 sY[16 * 264];
    __shared__ float scL[32], soL[32];
    int tid = threadIdx.x;
    int w = tid >> 6, l = tid & 63, q = l >> 4, r = l & 15;
    int rowBase = blockIdx.x * 16;
    f32x4 z = {0.f, 0.f, 0.f, 0.f};

    if (tid < 32) {                     // layer-3 BN stats from 8 shadows
        float sm = 0.f, sq = 0.f;
#pragma unroll
        for (int s = 0; s < 8; ++s) { sm += bns3[s * 64 + tid]; sq += bns3[s * 64 + 32 + tid]; }
        const float inv_n = 1.0f / (float)NN;
        float mean = sm * inv_n;
        float var = sq * inv_n - mean * mean;
        float sc = g3[tid] * rsqrtf(var + EPS);
        scL[tid] = sc;
        soL[tid] = b3[tid] - mean * sc;
    }
    __syncthreads();
    float scr[8], sor[8];               // this thread's constant channel window
#pragma unroll
    for (int j = 0; j < 8; ++j) { scr[j] = scL[q * 8 + j]; sor[j] = soL[q * 8 + j]; }

    // ---- stage 1: sX = relu(bnrelu(Y)[16x1024] @ W1T^T + mb1) ----
    {
        f32x4 acc[4] = {z, z, z, z};
        const float* yp = Y + (size_t)(rowBase + r) * 1024 + q * 8;
        for (int k0 = 0; k0 < 1024; k0 += 32) {
            float4 ya = *(const float4*)(yp + k0);
            float4 yb = *(const float4*)(yp + k0 + 4);
            f16x8 a0;
            a0[0] = (_Float16)fmaxf(ya.x * scr[0] + sor[0], 0.f);
            a0[1] = (_Float16)fmaxf(ya.y * scr[1] + sor[1], 0.f);
            a0[2] = (_Float16)fmaxf(ya.z * scr[2] + sor[2], 0.f);
            a0[3] = (_Float16)fmaxf(ya.w * scr[3] + sor[3], 0.f);
            a0[4] = (_Float16)fmaxf(yb.x * scr[4] + sor[4], 0.f);
            a0[5] = (_Float16)fmaxf(yb.y * scr[5] + sor[5], 0.f);
            a0[6] = (_Float16)fmaxf(yb.z * scr[6] + sor[6], 0.f);
            a0[7] = (_Float16)fmaxf(yb.w * scr[7] + sor[7], 0.f);
#pragma unroll
            for (int ct = 0; ct < 4; ++ct) {
                int col = ct * 64 + w * 16 + r;
                f16x8 bf = *(const f16x8*)(W1T + (size_t)col * 1024 + q * 8 + k0);
                acc[ct] = __builtin_amdgcn_mfma_f32_16x16x32_f16(a0, bf, acc[ct], 0, 0, 0);
            }
        }
#pragma unroll
        for (int ct = 0; ct < 4; ++ct) {
            int col = ct * 64 + w * 16 + r;
            float bv = mb1[col];
#pragma unroll
            for (int i = 0; i < 4; ++i)
                sX[(q * 4 + i) * 264 + col] = (_Float16)fmaxf(acc[ct][i] + bv, 0.f);
        }
    }
    __syncthreads();

    // ---- stage 2: sY = relu(sX @ W2T^T + mb2) ----
    {
        f32x4 acc[4] = {z, z, z, z};
        for (int k0 = 0; k0 < 256; k0 += 32) {
            f16x8 a0 = *(const f16x8*)(sX + r * 264 + q * 8 + k0);
#pragma unroll
            for (int ct = 0; ct < 4; ++ct) {
                int col = ct * 64 + w * 16 + r;
                f16x8 bf = *(const f16x8*)(W2T + (size_t)col * 256 + q * 8 + k0);
                acc[ct] = __builtin_amdgcn_mfma_f32_16x16x32_f16(a0, bf, acc[ct], 0, 0, 0);
            }
        }
#pragma unroll
        for (int ct = 0; ct < 4; ++ct) {
            int col = ct * 64 + w * 16 + r;
            float bv = mb2[col];
#pragma unroll
            for (int i = 0; i < 4; ++i)
                sY[(q * 4 + i) * 264 + col] = (_Float16)fmaxf(acc[ct][i] + bv, 0.f);
        }
    }
    __syncthreads();

    // ---- stage 3: sX = relu(sY @ W3T^T + mb3) ----
    {
        f32x4 acc[4] = {z, z, z, z};
        for (int k0 = 0; k0 < 256; k0 += 32) {
            f16x8 a0 = *(const f16x8*)(sY + r * 264 + q * 8 + k0);
#pragma unroll
            for (int ct = 0; ct < 4; ++ct) {
                int col = ct * 64 + w * 16 + r;
                f16x8 bf = *(const f16x8*)(W3T + (size_t)col * 256 + q * 8 + k0);
                acc[ct] = __builtin_amdgcn_mfma_f32_16x16x32_f16(a0, bf, acc[ct], 0, 0, 0);
            }
        }
        __syncthreads();                // stage-2 sX reads done block-wide before overwrite
#pragma unroll
        for (int ct = 0; ct < 4; ++ct) {
            int col = ct * 64 + w * 16 + r;
            float bv = mb3[col];
#pragma unroll
            for (int i = 0; i < 4; ++i)
                sX[(q * 4 + i) * 264 + col] = (_Float16)fmaxf(acc[ct][i] + bv, 0.f);
        }
    }
    __syncthreads();

    // ---- stage 4: out[16x64] = sX @ BqT^T + biasq (no relu, fp32 out) ----
    {
        f32x4 acc = z;
        int col = w * 16 + r;
        for (int k0 = 0; k0 < 256; k0 += 32) {
            f16x8 a0 = *(const f16x8*)(sX + r * 264 + q * 8 + k0);
            f16x8 bf = *(const f16x8*)(BqT + (size_t)col * 256 + q * 8 + k0);
            acc = __builtin_amdgcn_mfma_f32_16x16x32_f16(a0, bf, acc, 0, 0, 0);
        }
        float bv = biasq[col];
#pragma unroll
        for (int i = 0; i < 4; ++i)
            out[(size_t)(rowBase + q * 4 + i) * 64 + col] = acc[i] + bv;
    }
}

extern "C" void kernel_launch(void* const* d_in, const int* in_sizes, int n_in,
                              void* d_out, int out_size, void* d_ws, size_t ws_size,
                              hipStream_t stream) {
    const float* x    = (const float*)d_in[0];
    const int*   ei   = (const int*)d_in[1];
    const float* c1W1 = (const float*)d_in[2];
    const float* c1b1 = (const float*)d_in[3];
    const float* c1W2 = (const float*)d_in[4];
    const float* c1b2 = (const float*)d_in[5];
    const float* c2W1 = (const float*)d_in[6];
    const float* c2b1 = (const float*)d_in[7];
    const float* c2W2 = (const float*)d_in[8];
    const float* c2b2 = (const float*)d_in[9];
    const float* c3W1 = (const float*)d_in[10];
    const float* c3b1 = (const float*)d_in[11];
    const float* c3W2 = (const float*)d_in[12];
    const float* c3b2 = (const float*)d_in[13];
    const float* bn_g = (const float*)d_in[14];
    const float* bn_b = (const float*)d_in[15];
    const float* mW1  = (const float*)d_in[16];
    const float* mb1  = (const float*)d_in[17];
    const float* mW2  = (const float*)d_in[18];
    const float* mb2  = (const float*)d_in[19];
    const float* mW3  = (const float*)d_in[20];
    const float* mb3  = (const float*)d_in[21];
    const float* vW   = (const float*)d_in[22];
    const float* vb   = (const float*)d_in[23];
    const float* aW   = (const float*)d_in[24];
    const float* ab   = (const float*)d_in[25];
    float* out = (float*)d_out;

    char* p = (char*)d_ws;
    auto take = [&](size_t bytes) {
        char* r = p;
        p += (bytes + 255) & ~(size_t)255;
        return r;
    };
    int*       gcount = (int*)take((size_t)BKT * 4);
    int*       words  = (int*)take((size_t)BKT * CAP * 4);       // ~10 MB bucketed edges
    int*       ssrc   = (int*)take((size_t)BKT * SCAP * 4);      // 16 MB padded CSR srcs
    int*       offs   = (int*)take((size_t)NN * 4);
    int*       offe   = (int*)take((size_t)NN * 4);
    float*     u      = (float*)take((size_t)NN * HH * 4);
    __half*    v      = (__half*)take((size_t)(NN + 1) * HH * 2);
    float*     y      = (float*)take((size_t)NN * SS * 4);
    float*     bns    = (float*)take(3 * 512 * 4);               // 3 layers x 8 shadows x 64
    _Float16*  W1T    = (_Float16*)take((size_t)256 * 1024 * 2);
    _Float16*  W2T    = (_Float16*)take((size_t)256 * 256 * 2);
    _Float16*  W3T    = (_Float16*)take((size_t)256 * 256 * 2);
    _Float16*  BqT    = (_Float16*)take((size_t)64 * 256 * 2);
    float*     biasq  = (float*)take(64 * 4);

    // fused prep (weight transposes + head fold + zero-init + layer-1 pre-transform)
    k_prep<<<NN * 16 / 256, 256, 0, stream>>>(mW1, mW2, mW3, vW, vb, aW, ab,
                                              W1T, W2T, W3T, BqT, biasq, gcount, bns,
                                              x, c1W1, c1b1, u, v);

    // CSR build: LDS-staged bucket partition (1024 thr), then padded within-bucket sort
    k_bsort<<<EE / TILE, 1024, 0, stream>>>(ei, gcount, words);
    k_csr<<<BKT, 512, 0, stream>>>(words, gcount, ssrc, offs, offe);

    // layer 1 (gather + fused BN stats)
    k_gather<<<NN / 64, 256, 0, stream>>>(u, v, ssrc, offs, offe, c1W2, c1b2, y, bns);
    // layer 2 (fused BN+ReLU+pre, 64 nodes/block)
    k_bnpre<<<NN / 64, 256, 0, stream>>>(y, bns, bn_g, bn_b, c2W1, c2b1, u, v);
    k_gather<<<NN / 64, 256, 0, stream>>>(u, v, ssrc, offs, offe, c2W2, c2b2, y, bns + 512);
    // layer 3 (fused BN+ReLU+pre, 64 nodes/block)
    k_bnpre<<<NN / 64, 256, 0, stream>>>(y, bns + 512, bn_g + 32, bn_b + 32, c3W1, c3b1, u, v);
    k_gather<<<NN / 64, 256, 0, stream>>>(u, v, ssrc, offs, offe, c3W2, c3b2, y, bns + 1024);

    // dense head MLP + dueling head: one fused MFMA kernel with inline layer-3 BN+ReLU
    k_mlp<<<BB / 16, 256, 0, stream>>>(y, bns + 1024, bn_g + 64, bn_b + 64,
                                       W1T, W2T, W3T, BqT, mb1, mb2, mb3, biasq, out);
}

// Round 12
// 297.348 us; speedup vs baseline: 1.0264x; 1.0264x over previous
//
#include <hip/hip_runtime.h>
#include <hip/hip_fp16.h>

#define NN 131072        // nodes
#define EE 2097152       // edges
#define SS 32            // channels
#define HH 16            // hidden
#define BB 4096          // graphs
#define EPS 1e-5f

#define BKT 512          // buckets (dst >> 8)
#define BNODES 256       // nodes per bucket
#define CAP 4864         // bucket capacity in words (avg 4096, +12 sigma)
#define SCAP 8192        // bucket capacity in ssrc (padded-to-8 per node)
#define TILE 8192        // edges per bsort block

typedef _Float16 f16x8 __attribute__((ext_vector_type(8)));
typedef float f32x4 __attribute__((ext_vector_type(4)));

// ---------------- bucket partition, LDS-staged, 1024 threads ----------------
__global__ __launch_bounds__(1024) void k_bsort(const int* __restrict__ ei, int* __restrict__ gcount,
                                                int* __restrict__ words) {
    __shared__ int cnt[BKT];
    __shared__ int tstart[BKT];
    __shared__ int gshift[BKT];
    __shared__ int sc[BKT];
    __shared__ int sword[TILE];
    __shared__ int sdst[TILE];
    int t = threadIdx.x;
    if (t < BKT) cnt[t] = 0;
    __syncthreads();
    int e0 = blockIdx.x * TILE;
    int dreg[TILE / 1024];
#pragma unroll
    for (int it = 0; it < TILE / 1024; ++it) {
        dreg[it] = ei[EE + e0 + it * 1024 + t];
        atomicAdd(&cnt[dreg[it] >> 8], 1);
    }
    __syncthreads();
    int val = (t < BKT) ? cnt[t] : 0;
    if (t < BKT) sc[t] = val;
    __syncthreads();
    for (int d = 1; d < BKT; d <<= 1) {
        int v2 = (t >= d && t < BKT) ? sc[t - d] : 0;
        __syncthreads();
        if (t < BKT) sc[t] += v2;
        __syncthreads();
    }
    if (t < BKT) {
        int excl = sc[t] - val;
        tstart[t] = excl;
        gshift[t] = t * CAP + atomicAdd(&gcount[t], val) - excl;   // includes segment base
        cnt[t] = 0;                     // reuse as intra-tile cursor
    }
    __syncthreads();
#pragma unroll
    for (int it = 0; it < TILE / 1024; ++it) {
        int e = e0 + it * 1024 + t;
        int src = ei[e];
        int dst = dreg[it];
        int b = dst >> 8;
        int r = atomicAdd(&cnt[b], 1);
        int p = tstart[b] + r;
        sword[p] = src | ((dst & 255) << 17);
        sdst[p] = gshift[b] + p;        // == b*CAP + bucket_base + rank
    }
    __syncthreads();
#pragma unroll
    for (int it = 0; it < TILE / 1024; ++it) {
        int i = it * 1024 + t;
        words[sdst[i]] = sword[i];      // position-ordered: full-line bursts
    }
}

// ---------------- within-bucket sort to CSR with 8-padded node segments ----------------
// R12: reverted R11's LDS-stash (regressed ~7us); two-pass words read, 2nd L2-hot.
__global__ __launch_bounds__(512) void k_csr(const int* __restrict__ words, const int* __restrict__ gcount,
                                             int* __restrict__ ssrc, int* __restrict__ offs,
                                             int* __restrict__ offe) {
    __shared__ int hist[BNODES];
    __shared__ int sc[BNODES];
    __shared__ int base[BNODES];
    int t = threadIdx.x;
    int b = blockIdx.x;
    if (t < BNODES) hist[t] = 0;
    __syncthreads();
    int cnt = gcount[b];
    const int* wp = words + (size_t)b * CAP;
    for (int p = t; p < cnt; p += 512) atomicAdd(&hist[wp[p] >> 17], 1);
    __syncthreads();
    int val = 0, pval = 0;
    if (t < BNODES) {
        val = hist[t];
        pval = (val + 7) & ~7;          // padded length (pad-8)
        sc[t] = pval;
    }
    __syncthreads();
    for (int d = 1; d < BNODES; d <<= 1) {
        int v2 = (t >= d && t < BNODES) ? sc[t - d] : 0;
        __syncthreads();
        if (t < BNODES) sc[t] += v2;
        __syncthreads();
    }
    int gbase = b * SCAP;
    if (t < BNODES) {
        base[t] = sc[t] - pval;         // exclusive scan of padded lengths
        offs[b * BNODES + t] = gbase + base[t];
        offe[b * BNODES + t] = gbase + base[t] + val;
        hist[t] = 0;                    // reuse as per-node cursor
    }
    __syncthreads();
    for (int p = t; p < cnt; p += 512) {
        int w = wp[p];                  // L2-hot re-read
        int dl = w >> 17;
        int r = atomicAdd(&hist[dl], 1);
        ssrc[gbase + base[dl] + r] = w & 0x1FFFF;
    }
    if (t < BNODES) {                   // pad fill: disjoint range [val, pval)
        int s = gbase + base[t];
        for (int i = val; i < pval; ++i) ssrc[s + i] = NN;
    }
}

// ---------------- fused prep: weight transposes + head fold + zero-init + layer-1 pre ----------------
__global__ __launch_bounds__(256) void k_prep(const float* __restrict__ mW1, const float* __restrict__ mW2,
                                              const float* __restrict__ mW3, const float* __restrict__ vW,
                                              const float* __restrict__ vb, const float* __restrict__ aW,
                                              const float* __restrict__ ab,
                                              _Float16* __restrict__ W1T, _Float16* __restrict__ W2T,
                                              _Float16* __restrict__ W3T, _Float16* __restrict__ BqT,
                                              float* __restrict__ biasq, int* __restrict__ gcount,
                                              float* __restrict__ bns,
                                              const float* __restrict__ x, const float* __restrict__ c1W1,
                                              const float* __restrict__ c1b1,
                                              float* __restrict__ u, __half* __restrict__ v) {
    int i = blockIdx.x * 256 + threadIdx.x;     // NN*16 = 2097152 threads
    {   // layer-1 pre-transform for every (node, hidden-ch)
        int n = i >> 4, c = i & 15;
        float x0 = x[n * 2], x1 = x[n * 2 + 1];
        float w0 = c1W1[c], w1 = c1W1[16 + c], w2 = c1W1[32 + c], w3 = c1W1[48 + c];
        u[i] = c1b1[c] + x0 * (w0 - w2) + x1 * (w1 - w3);
        v[i] = __float2half(x0 * w2 + x1 * w3);
    }
    if (i < 262144) {
        int k = i >> 8, n = i & 255;
        W1T[(size_t)n * 1024 + k] = (_Float16)mW1[i];
    }
    if (i < 65536) {
        int k = i >> 8, n = i & 255;
        W2T[n * 256 + k] = (_Float16)mW2[i];
        W3T[n * 256 + k] = (_Float16)mW3[i];
    }
    if (i < 16384) {
        int f = i >> 6, j = i & 63;
        int n = j >> 1, a = j & 1;
        float wa = aW[n * 512 + f * 2 + a];
        float wo = aW[n * 512 + f * 2 + (1 - a)];
        BqT[j * 256 + f] = (_Float16)(vW[f] + 0.5f * (wa - wo));
    }
    if (i < 64) biasq[i] = vb[0] + 0.5f * (ab[i] - ab[i ^ 1]);
    if (i < 512) gcount[i] = 0;
    if (i < 1536) bns[i] = 0.f;                 // 3 layers x 8 shadows x 64
    if (i < 16) v[NN * 16 + i] = __float2half(-60000.0f);
}

// ---------------- fused BN+ReLU + pre-transform for layers 2/3 ----------------
// R12: reverted to 16 nodes/block (R11's 64/block regressed).
__global__ __launch_bounds__(256) void k_bnpre(const float* __restrict__ y, const float* __restrict__ bns,
                                               const float* __restrict__ g, const float* __restrict__ bb,
                                               const float* __restrict__ W1, const float* __restrict__ b1,
                                               float* __restrict__ u, __half* __restrict__ v) {
    __shared__ float sh[16][33];
    __shared__ float wd[32][16];
    __shared__ float wv[32][16];
    __shared__ float scL[32], soL[32];
    int t = threadIdx.x;
    if (t < 32) {
        float sm = 0.f, sq = 0.f;
#pragma unroll
        for (int s = 0; s < 8; ++s) { sm += bns[s * 64 + t]; sq += bns[s * 64 + 32 + t]; }
        const float inv_n = 1.0f / (float)NN;
        float mean = sm * inv_n;
        float var = sq * inv_n - mean * mean;
        float s2 = g[t] * rsqrtf(var + EPS);
        scL[t] = s2;
        soL[t] = bb[t] - mean * s2;
    }
    for (int i = t; i < 512; i += 256) {
        int f = i >> 4, c = i & 15;
        float wt = W1[i];
        float wb = W1[512 + i];
        wd[f][c] = wt - wb;
        wv[f][c] = wb;
    }
    __syncthreads();
    int nb = blockIdx.x * 16;
    for (int i = t; i < 512; i += 256) {
        int col = i & 31;
        sh[i >> 5][col] = fmaxf(y[nb * 32 + i] * scL[col] + soL[col], 0.f);
    }
    __syncthreads();
    int c = t & 15, nl = t >> 4;
    float uu = b1[c], vv = 0.f;
#pragma unroll
    for (int f = 0; f < 32; ++f) {
        float hv = sh[nl][f];
        uu += hv * wd[f][c];
        vv += hv * wv[f][c];
    }
    int n = nb + nl;
    u[n * 16 + c] = uu;
    v[n * 16 + c] = __float2half(vv);
    if (blockIdx.x == 0 && t < 16) v[NN * 16 + t] = __float2half(-60000.0f);
}

// ---------------- CSR gather + fused BN-stat accumulation ----------------
__global__ __launch_bounds__(256) void k_gather(const float* __restrict__ u, const __half* __restrict__ v,
                                                const int* __restrict__ ssrc, const int* __restrict__ offs,
                                                const int* __restrict__ offe,
                                                const float* __restrict__ W2, const float* __restrict__ b2,
                                                float* __restrict__ y, float* __restrict__ bns) {
    __shared__ float sw2[512];          // [k][32]
    __shared__ float sagg[64 * 17];
    __shared__ float cntL[64];
    __shared__ float ssum[32];
    __shared__ float ssq[32];
    int t = threadIdx.x;
    if (t < 32) { ssum[t] = 0.f; ssq[t] = 0.f; }
    float w2a = W2[t], w2b = W2[t + 256];         // stage in regs; LDS write after gather
    float b2r0 = b2[(t & 7) * 4], b2r1 = b2[(t & 7) * 4 + 1];
    float b2r2 = b2[(t & 7) * 4 + 2], b2r3 = b2[(t & 7) * 4 + 3];
    int nl = t >> 2, c4 = t & 3;        // 64 nodes/block, 4 threads/node
    int n = blockIdx.x * 64 + nl;
    int s0 = offs[n], e0 = offe[n];
    int pe = s0 + ((e0 - s0 + 7) & ~7);           // padded end (pad slots -> node NN -> relu 0)
    float4 uc = *(const float4*)(u + (size_t)n * 16 + 4 * c4);
    float a0 = 0.f, a1 = 0.f, a2 = 0.f, a3 = 0.f;
    for (int p = s0; p < pe; p += 8) {
        int idx[8];
#pragma unroll
        for (int i = 0; i < 8; ++i) idx[i] = ssrc[p + i];
        uint2 hv[8];
#pragma unroll
        for (int i = 0; i < 8; ++i)
            hv[i] = *(const uint2*)(v + (size_t)idx[i] * 16 + 4 * c4);
#pragma unroll
        for (int i = 0; i < 8; ++i) {
            float2 f01 = __half22float2(*(const __half2*)&hv[i].x);
            float2 f23 = __half22float2(*(const __half2*)&hv[i].y);
            a0 += fmaxf(uc.x + f01.x, 0.f);
            a1 += fmaxf(uc.y + f01.y, 0.f);
            a2 += fmaxf(uc.z + f23.x, 0.f);
            a3 += fmaxf(uc.w + f23.y, 0.f);
        }
    }
    sagg[nl * 17 + 4 * c4]     = a0;
    sagg[nl * 17 + 4 * c4 + 1] = a1;
    sagg[nl * 17 + 4 * c4 + 2] = a2;
    sagg[nl * 17 + 4 * c4 + 3] = a3;
    if (c4 == 0) cntL[nl] = (float)(e0 - s0);
    sw2[t] = w2a;
    sw2[t + 256] = w2b;
    __syncthreads();
#pragma unroll
    for (int h = 0; h < 2; ++h) {       // two 32-node passes of the proven epilogue
        int node = h * 32 + (t >> 3), oc = (t & 7) * 4;
        float cw = cntL[node];
        float o0 = b2r0 * cw, o1 = b2r1 * cw, o2 = b2r2 * cw, o3 = b2r3 * cw;
#pragma unroll
        for (int k = 0; k < 16; ++k) {
            float a = sagg[node * 17 + k];
            o0 += a * sw2[k * 32 + oc];
            o1 += a * sw2[k * 32 + oc + 1];
            o2 += a * sw2[k * 32 + oc + 2];
            o3 += a * sw2[k * 32 + oc + 3];
        }
        *(float4*)(y + (size_t)(blockIdx.x * 64 + node) * 32 + oc) = make_float4(o0, o1, o2, o3);
        // fused BN stats: reduce o and o^2 over the 8 nodes of this wave
        float q0 = o0 * o0, q1 = o1 * o1, q2 = o2 * o2, q3 = o3 * o3;
#pragma unroll
        for (int m = 8; m < 64; m <<= 1) {
            o0 += __shfl_xor(o0, m); o1 += __shfl_xor(o1, m);
            o2 += __shfl_xor(o2, m); o3 += __shfl_xor(o3, m);
            q0 += __shfl_xor(q0, m); q1 += __shfl_xor(q1, m);
            q2 += __shfl_xor(q2, m); q3 += __shfl_xor(q3, m);
        }
        if ((t & 63) < 8) {             // one lane per channel-quad per wave
            atomicAdd(&ssum[oc], o0);     atomicAdd(&ssum[oc + 1], o1);
            atomicAdd(&ssum[oc + 2], o2); atomicAdd(&ssum[oc + 3], o3);
            atomicAdd(&ssq[oc], q0);      atomicAdd(&ssq[oc + 1], q1);
            atomicAdd(&ssq[oc + 2], q2);  atomicAdd(&ssq[oc + 3], q3);
        }
    }
    __syncthreads();
    if (t < 64) {
        float val = (t < 32) ? ssum[t] : ssq[t - 32];
        atomicAdd(&bns[(blockIdx.x & 7) * 64 + t], val);
    }
}

// ---------------- fused MLP + dueling head (+ layer-3 BN+ReLU inline) ----------------
__global__ __launch_bounds__(256) void k_mlp(const float* __restrict__ Y, const float* __restrict__ bns3,
                                             const float* __restrict__ g3, const float* __restrict__ b3,
                                             const _Float16* __restrict__ W1T,
                                             const _Float16* __restrict__ W2T, const _Float16* __restrict__ W3T,
                                             const _Float16* __restrict__ BqT,
                                             const float* __restrict__ mb1, const float* __restrict__ mb2,
                                             const float* __restrict__ mb3, const float* __restrict__ biasq,
                                             float* __restrict__ out) {
    __shared__ _Float16 sX[16 * 264];
    __shared__ _Float16 sY[16 * 264];
    __shared__ float scL[32], soL[32];
    int tid = threadIdx.x;
    int w = tid >> 6, l = tid & 63, q = l >> 4, r = l & 15;
    int rowBase = blockIdx.x * 16;
    f32x4 z = {0.f, 0.f, 0.f, 0.f};

    if (tid < 32) {                     // layer-3 BN stats from 8 shadows
        float sm = 0.f, sq = 0.f;
#pragma unroll
        for (int s = 0; s < 8; ++s) { sm += bns3[s * 64 + tid]; sq += bns3[s * 64 + 32 + tid]; }
        const float inv_n = 1.0f / (float)NN;
        float mean = sm * inv_n;
        float var = sq * inv_n - mean * mean;
        float sc = g3[tid] * rsqrtf(var + EPS);
        scL[tid] = sc;
        soL[tid] = b3[tid] - mean * sc;
    }
    __syncthreads();
    float scr[8], sor[8];               // this thread's constant channel window
#pragma unroll
    for (int j = 0; j < 8; ++j) { scr[j] = scL[q * 8 + j]; sor[j] = soL[q * 8 + j]; }

    // ---- stage 1: sX = relu(bnrelu(Y)[16x1024] @ W1T^T + mb1) ----
    {
        f32x4 acc[4] = {z, z, z, z};
        const float* yp = Y + (size_t)(rowBase + r) * 1024 + q * 8;
        for (int k0 = 0; k0 < 1024; k0 += 32) {
            float4 ya = *(const float4*)(yp + k0);
            float4 yb = *(const float4*)(yp + k0 + 4);
            f16x8 a0;
            a0[0] = (_Float16)fmaxf(ya.x * scr[0] + sor[0], 0.f);
            a0[1] = (_Float16)fmaxf(ya.y * scr[1] + sor[1], 0.f);
            a0[2] = (_Float16)fmaxf(ya.z * scr[2] + sor[2], 0.f);
            a0[3] = (_Float16)fmaxf(ya.w * scr[3] + sor[3], 0.f);
            a0[4] = (_Float16)fmaxf(yb.x * scr[4] + sor[4], 0.f);
            a0[5] = (_Float16)fmaxf(yb.y * scr[5] + sor[5], 0.f);
            a0[6] = (_Float16)fmaxf(yb.z * scr[6] + sor[6], 0.f);
            a0[7] = (_Float16)fmaxf(yb.w * scr[7] + sor[7], 0.f);
#pragma unroll
            for (int ct = 0; ct < 4; ++ct) {
                int col = ct * 64 + w * 16 + r;
                f16x8 bf = *(const f16x8*)(W1T + (size_t)col * 1024 + q * 8 + k0);
                acc[ct] = __builtin_amdgcn_mfma_f32_16x16x32_f16(a0, bf, acc[ct], 0, 0, 0);
            }
        }
#pragma unroll
        for (int ct = 0; ct < 4; ++ct) {
            int col = ct * 64 + w * 16 + r;
            float bv = mb1[col];
#pragma unroll
            for (int i = 0; i < 4; ++i)
                sX[(q * 4 + i) * 264 + col] = (_Float16)fmaxf(acc[ct][i] + bv, 0.f);
        }
    }
    __syncthreads();

    // ---- stage 2: sY = relu(sX @ W2T^T + mb2) ----
    {
        f32x4 acc[4] = {z, z, z, z};
        for (int k0 = 0; k0 < 256; k0 += 32) {
            f16x8 a0 = *(const f16x8*)(sX + r * 264 + q * 8 + k0);
#pragma unroll
            for (int ct = 0; ct < 4; ++ct) {
                int col = ct * 64 + w * 16 + r;
                f16x8 bf = *(const f16x8*)(W2T + (size_t)col * 256 + q * 8 + k0);
                acc[ct] = __builtin_amdgcn_mfma_f32_16x16x32_f16(a0, bf, acc[ct], 0, 0, 0);
            }
        }
#pragma unroll
        for (int ct = 0; ct < 4; ++ct) {
            int col = ct * 64 + w * 16 + r;
            float bv = mb2[col];
#pragma unroll
            for (int i = 0; i < 4; ++i)
                sY[(q * 4 + i) * 264 + col] = (_Float16)fmaxf(acc[ct][i] + bv, 0.f);
        }
    }
    __syncthreads();

    // ---- stage 3: sX = relu(sY @ W3T^T + mb3) ----
    {
        f32x4 acc[4] = {z, z, z, z};
        for (int k0 = 0; k0 < 256; k0 += 32) {
            f16x8 a0 = *(const f16x8*)(sY + r * 264 + q * 8 + k0);
#pragma unroll
            for (int ct = 0; ct < 4; ++ct) {
                int col = ct * 64 + w * 16 + r;
                f16x8 bf = *(const f16x8*)(W3T + (size_t)col * 256 + q * 8 + k0);
                acc[ct] = __builtin_amdgcn_mfma_f32_16x16x32_f16(a0, bf, acc[ct], 0, 0, 0);
            }
        }
        __syncthreads();                // stage-2 sX reads done block-wide before overwrite
#pragma unroll
        for (int ct = 0; ct < 4; ++ct) {
            int col = ct * 64 + w * 16 + r;
            float bv = mb3[col];
#pragma unroll
            for (int i = 0; i < 4; ++i)
                sX[(q * 4 + i) * 264 + col] = (_Float16)fmaxf(acc[ct][i] + bv, 0.f);
        }
    }
    __syncthreads();

    // ---- stage 4: out[16x64] = sX @ BqT^T + biasq (no relu, fp32 out) ----
    {
        f32x4 acc = z;
        int col = w * 16 + r;
        for (int k0 = 0; k0 < 256; k0 += 32) {
            f16x8 a0 = *(const f16x8*)(sX + r * 264 + q * 8 + k0);
            f16x8 bf = *(const f16x8*)(BqT + (size_t)col * 256 + q * 8 + k0);
            acc = __builtin_amdgcn_mfma_f32_16x16x32_f16(a0, bf, acc, 0, 0, 0);
        }
        float bv = biasq[col];
#pragma unroll
        for (int i = 0; i < 4; ++i)
            out[(size_t)(rowBase + q * 4 + i) * 64 + col] = acc[i] + bv;
    }
}

extern "C" void kernel_launch(void* const* d_in, const int* in_sizes, int n_in,
                              void* d_out, int out_size, void* d_ws, size_t ws_size,
                              hipStream_t stream) {
    const float* x    = (const float*)d_in[0];
    const int*   ei   = (const int*)d_in[1];
    const float* c1W1 = (const float*)d_in[2];
    const float* c1b1 = (const float*)d_in[3];
    const float* c1W2 = (const float*)d_in[4];
    const float* c1b2 = (const float*)d_in[5];
    const float* c2W1 = (const float*)d_in[6];
    const float* c2b1 = (const float*)d_in[7];
    const float* c2W2 = (const float*)d_in[8];
    const float* c2b2 = (const float*)d_in[9];
    const float* c3W1 = (const float*)d_in[10];
    const float* c3b1 = (const float*)d_in[11];
    const float* c3W2 = (const float*)d_in[12];
    const float* c3b2 = (const float*)d_in[13];
    const float* bn_g = (const float*)d_in[14];
    const float* bn_b = (const float*)d_in[15];
    const float* mW1  = (const float*)d_in[16];
    const float* mb1  = (const float*)d_in[17];
    const float* mW2  = (const float*)d_in[18];
    const float* mb2  = (const float*)d_in[19];
    const float* mW3  = (const float*)d_in[20];
    const float* mb3  = (const float*)d_in[21];
    const float* vW   = (const float*)d_in[22];
    const float* vb   = (const float*)d_in[23];
    const float* aW   = (const float*)d_in[24];
    const float* ab   = (const float*)d_in[25];
    float* out = (float*)d_out;

    char* p = (char*)d_ws;
    auto take = [&](size_t bytes) {
        char* r = p;
        p += (bytes + 255) & ~(size_t)255;
        return r;
    };
    int*       gcount = (int*)take((size_t)BKT * 4);
    int*       words  = (int*)take((size_t)BKT * CAP * 4);       // ~10 MB bucketed edges
    int*       ssrc   = (int*)take((size_t)BKT * SCAP * 4);      // 16 MB padded CSR srcs
    int*       offs   = (int*)take((size_t)NN * 4);
    int*       offe   = (int*)take((size_t)NN * 4);
    float*     u      = (float*)take((size_t)NN * HH * 4);
    __half*    v      = (__half*)take((size_t)(NN + 1) * HH * 2);
    float*     y      = (float*)take((size_t)NN * SS * 4);
    float*     bns    = (float*)take(3 * 512 * 4);               // 3 layers x 8 shadows x 64
    _Float16*  W1T    = (_Float16*)take((size_t)256 * 1024 * 2);
    _Float16*  W2T    = (_Float16*)take((size_t)256 * 256 * 2);
    _Float16*  W3T    = (_Float16*)take((size_t)256 * 256 * 2);
    _Float16*  BqT    = (_Float16*)take((size_t)64 * 256 * 2);
    float*     biasq  = (float*)take(64 * 4);

    // fused prep (weight transposes + head fold + zero-init + layer-1 pre-transform)
    k_prep<<<NN * 16 / 256, 256, 0, stream>>>(mW1, mW2, mW3, vW, vb, aW, ab,
                                              W1T, W2T, W3T, BqT, biasq, gcount, bns,
                                              x, c1W1, c1b1, u, v);

    // CSR build: LDS-staged bucket partition (1024 thr), then padded within-bucket sort
    k_bsort<<<EE / TILE, 1024, 0, stream>>>(ei, gcount, words);
    k_csr<<<BKT, 512, 0, stream>>>(words, gcount, ssrc, offs, offe);

    // layer 1 (gather + fused BN stats)
    k_gather<<<NN / 64, 256, 0, stream>>>(u, v, ssrc, offs, offe, c1W2, c1b2, y, bns);
    // layer 2 (fused BN+ReLU+pre)
    k_bnpre<<<NN / 16, 256, 0, stream>>>(y, bns, bn_g, bn_b, c2W1, c2b1, u, v);
    k_gather<<<NN / 64, 256, 0, stream>>>(u, v, ssrc, offs, offe, c2W2, c2b2, y, bns + 512);
    // layer 3 (fused BN+ReLU+pre)
    k_bnpre<<<NN / 16, 256, 0, stream>>>(y, bns + 512, bn_g + 32, bn_b + 32, c3W1, c3b1, u, v);
    k_gather<<<NN / 64, 256, 0, stream>>>(u, v, ssrc, offs, offe, c3W2, c3b2, y, bns + 1024);

    // dense head MLP + dueling head: one fused MFMA kernel with inline layer-3 BN+ReLU
    k_mlp<<<BB / 16, 256, 0, stream>>>(y, bns + 1024, bn_g + 64, bn_b + 64,
                                       W1T, W2T, W3T, BqT, mb1, mb2, mb3, biasq, out);
}